// Round 11
// baseline (65.493 us; speedup 1.0000x reference)
//
#include <hip/hip_runtime.h>

#define NN 8192
#define DD 128
#define BM 128
#define NTILE (NN / BM)   // 64

typedef __attribute__((ext_vector_type(8))) short bf16x8;
typedef __attribute__((ext_vector_type(4))) float f32x4;

__device__ __forceinline__ ushort f2bf(float x) {
    unsigned u = __float_as_uint(x);
    unsigned r = u + 0x7FFFu + ((u >> 16) & 1u);
    return (ushort)(r >> 16);
}

__device__ __forceinline__ void async16(void* lds, const void* g) {
    __builtin_amdgcn_global_load_lds(
        (const __attribute__((address_space(1))) unsigned*)g,
        (__attribute__((address_space(3))) unsigned*)lds, 16, 0, 0);
}
__device__ __forceinline__ void async4(void* lds, const void* g) {
    __builtin_amdgcn_global_load_lds(
        (const __attribute__((address_space(1))) unsigned*)g,
        (__attribute__((address_space(3))) unsigned*)lds, 4, 0, 0);
}

// Kernel 0: sq[i] = ||f_i||^2 (always); Fbf = bf16(F) (if doFbf).
__global__ void prep_kernel(const float* __restrict__ F, ushort* __restrict__ Fbf,
                            float* __restrict__ sq, int doFbf) {
    int gtid = blockIdx.x * blockDim.x + threadIdx.x;
    int row  = gtid >> 6;
    int lane = threadIdx.x & 63;
    const float2 v = *(const float2*)(F + (size_t)row * DD + lane * 2);
    if (doFbf)
        ((ushort2*)(Fbf + (size_t)row * DD))[lane] = make_ushort2(f2bf(v.x), f2bf(v.y));
    float s = v.x * v.x + v.y * v.y;
    #pragma unroll
    for (int off = 32; off > 0; off >>= 1) s += __shfl_down(s, off);
    if (lane == 0) sq[row] = s;
}

// Kernel 1 (fast): per 128x128 S-tile, partial = sum S_ij*(sq_i+sq_j-2*f_i.f_j).
// R10 structure (measured 64.1us) with ONE change: S loads issued BEFORE the
// barrier, so the barrier's vmcnt(0) drain overlaps the S stream (HBM stays
// busy during the staging drain, killing the per-block S-less bubble).
__global__ __launch_bounds__(512, 4) void tile_kernel(
        const ushort* __restrict__ Fbf, const float* __restrict__ S,
        const float* __restrict__ sq, float* __restrict__ partials) {
    __shared__ ushort lI[BM * DD];   // F_i panel (B-operand), swizzled (32 KB)
    __shared__ ushort lJ[BM * DD];   // F_j panel (A-operand), swizzled (32 KB)
    __shared__ float  sqi[BM];
    __shared__ float  sqj[BM];
    __shared__ float  red[8];

    const int gi = blockIdx.y * BM, gj = blockIdx.x * BM;
    const int tid = threadIdx.x;
    const int w = tid >> 6, l = tid & 63;
    const int fr = l & 15;
    const int g  = l >> 4;
    const int jw = w * 16;            // wave's 16-col j window in tile

    // ---- (1) issue HBM S loads FIRST (DRAM starts ASAP) ----
    f32x4 sv[8];
    const float* sb = S + (size_t)(gi + fr) * NN + gj + jw + g * 4;
    #pragma unroll
    for (int ct = 0; ct < 8; ++ct)
        sv[ct] = *(const f32x4*)(sb + (size_t)ct * 16 * NN);
    __builtin_amdgcn_sched_barrier(0);

    // ---- (2) stage panels: linear LDS dest, pre-swizzled global src ----
    #pragma unroll
    for (int it = 0; it < 4; ++it) {
        const int chunk = it * 8 + w;            // 1 KB chunks, 32 per panel
        const int row = chunk * 4 + (l >> 4);    // LDS row this lane lands in
        const int src = ((l & 15) * 16) ^ ((row & 7) << 4);
        async16((char*)lI + chunk * 1024, (const char*)(Fbf + (size_t)(gi + row) * DD) + src);
        async16((char*)lJ + chunk * 1024, (const char*)(Fbf + (size_t)(gj + row) * DD) + src);
    }
    if (w < 4) {
        float* dstb = (w < 2 ? sqi : sqj) + (w & 1) * 64;
        const float* srcb = sq + (w < 2 ? gi : gj) + (w & 1) * 64 + l;
        async4(dstb, srcb);
    }
    __builtin_amdgcn_sched_barrier(0);

    // ---- (3) barrier: drains staging AND S (S keeps HBM busy meanwhile) ----
    __syncthreads();

    // ---- (4) A fragments from F_j panel ----
    bf16x8 afrag[4];
    #pragma unroll
    for (int kk = 0; kk < 4; ++kk) {
        const int row = jw + fr;
        int byte = row * 256 + kk * 64 + g * 16;
        byte ^= (row & 7) << 4;
        afrag[kk] = *(const bf16x8*)((const char*)lJ + byte);
    }

    f32x4 acc[8];
    #pragma unroll
    for (int ct = 0; ct < 8; ++ct) acc[ct] = (f32x4){0.f, 0.f, 0.f, 0.f};

    // ---- (5) MFMA: D = F_j . F_i^T ----
    #pragma unroll
    for (int ct = 0; ct < 8; ++ct) {
        const int row = ct * 16 + fr;
        const int sw  = (row & 7) << 4;
        #pragma unroll
        for (int kk = 0; kk < 4; ++kk) {
            const bf16x8 bfrag = *(const bf16x8*)((const char*)lI + row * 256 +
                                                  ((kk * 64 + g * 16) ^ sw));
            acc[ct] = __builtin_amdgcn_mfma_f32_16x16x32_bf16(afrag[kk], bfrag, acc[ct], 0, 0, 0);
        }
    }

    // ---- (6) consume: part += S * (sq_i + sq_j - 2*P) ----
    const float4 sjv = *(const float4*)(sqj + jw + g * 4);
    float part0 = 0.f, part1 = 0.f;
    #pragma unroll
    for (int ct = 0; ct < 8; ++ct) {
        const float sic = sqi[ct * 16 + fr];
        const f32x4 s4 = sv[ct];
        part0 += s4.x * ((sic + sjv.x) - 2.f * acc[ct][0]);
        part1 += s4.y * ((sic + sjv.y) - 2.f * acc[ct][1]);
        part0 += s4.z * ((sic + sjv.z) - 2.f * acc[ct][2]);
        part1 += s4.w * ((sic + sjv.w) - 2.f * acc[ct][3]);
    }
    float part = part0 + part1;

    // ---- (7) deterministic block reduction ----
    #pragma unroll
    for (int off = 32; off > 0; off >>= 1) part += __shfl_down(part, off);
    if (l == 0) red[w] = part;
    __syncthreads();
    if (tid == 0)
        partials[blockIdx.y * gridDim.x + blockIdx.x] =
            ((red[0] + red[1]) + (red[2] + red[3])) +
            ((red[4] + red[5]) + (red[6] + red[7]));
}

// ---------------- fallback path (tiny workspace): R2-style ----------------
__global__ __launch_bounds__(256, 2) void tile_fb_kernel(
        const float* __restrict__ F, const float* __restrict__ S,
        const float* __restrict__ sq, float* __restrict__ partials) {
    __shared__ ushort lI[BM * DD];
    __shared__ ushort lJ[BM * DD];
    __shared__ float  sqi[BM];
    __shared__ float  sqj[BM];
    __shared__ float  red[4];

    const int gi = blockIdx.y * BM, gj = blockIdx.x * BM;
    const int tid = threadIdx.x;
    const int w = tid >> 6, l = tid & 63;

    const int r0 = tid >> 5;
    const int c4 = (tid & 31) * 4;
    #pragma unroll
    for (int it = 0; it < 16; ++it) {
        const int row = it * 8 + r0;
        const float4 va = *(const float4*)(F + (size_t)(gi + row) * DD + c4);
        const float4 vb = *(const float4*)(F + (size_t)(gj + row) * DD + c4);
        int byte = row * 256 + c4 * 2;
        byte ^= (row & 7) << 4;
        *(ushort4*)((char*)lI + byte) =
            make_ushort4(f2bf(va.x), f2bf(va.y), f2bf(va.z), f2bf(va.w));
        *(ushort4*)((char*)lJ + byte) =
            make_ushort4(f2bf(vb.x), f2bf(vb.y), f2bf(vb.z), f2bf(vb.w));
    }
    if (tid < 128) sqi[tid] = sq[gi + tid];
    else           sqj[tid - 128] = sq[gj + tid - 128];
    __syncthreads();

    const int fr = l & 15;
    const int g  = l >> 4;
    const int jw = w * 32;

    float4 sv0[8], sv1[8];
    #pragma unroll
    for (int ct = 0; ct < 8; ++ct) {
        const float* srow = S + (size_t)(gi + ct * 16 + fr) * NN + gj + jw + g * 4;
        sv0[ct] = *(const float4*)(srow);
        sv1[ct] = *(const float4*)(srow + 16);
    }

    bf16x8 afrag[2][4];
    #pragma unroll
    for (int kk = 0; kk < 4; ++kk) {
        int row = jw + fr;
        int byte = row * 256 + kk * 64 + g * 16; byte ^= (row & 7) << 4;
        afrag[0][kk] = *(const bf16x8*)((const char*)lJ + byte);
        row = jw + 16 + fr;
        byte = row * 256 + kk * 64 + g * 16; byte ^= (row & 7) << 4;
        afrag[1][kk] = *(const bf16x8*)((const char*)lJ + byte);
    }

    f32x4 acc[2][8];
    #pragma unroll
    for (int ct = 0; ct < 8; ++ct) {
        acc[0][ct] = (f32x4){0.f, 0.f, 0.f, 0.f};
        acc[1][ct] = (f32x4){0.f, 0.f, 0.f, 0.f};
    }
    #pragma unroll
    for (int ct = 0; ct < 8; ++ct) {
        #pragma unroll
        for (int kk = 0; kk < 4; ++kk) {
            const int row = ct * 16 + fr;
            int byte = row * 256 + kk * 64 + g * 16; byte ^= (row & 7) << 4;
            const bf16x8 bfrag = *(const bf16x8*)((const char*)lI + byte);
            acc[0][ct] = __builtin_amdgcn_mfma_f32_16x16x32_bf16(afrag[0][kk], bfrag, acc[0][ct], 0, 0, 0);
            acc[1][ct] = __builtin_amdgcn_mfma_f32_16x16x32_bf16(afrag[1][kk], bfrag, acc[1][ct], 0, 0, 0);
        }
    }

    const float4 sj0 = *(const float4*)(sqj + jw + g * 4);
    const float4 sj1 = *(const float4*)(sqj + jw + 16 + g * 4);
    float part = 0.f;
    #pragma unroll
    for (int ct = 0; ct < 8; ++ct) {
        const float sic = sqi[ct * 16 + fr];
        const float4 s0 = sv0[ct], s1 = sv1[ct];
        part += s0.x * (sic + sj0.x - 2.f * acc[0][ct][0]);
        part += s0.y * (sic + sj0.y - 2.f * acc[0][ct][1]);
        part += s0.z * (sic + sj0.z - 2.f * acc[0][ct][2]);
        part += s0.w * (sic + sj0.w - 2.f * acc[0][ct][3]);
        part += s1.x * (sic + sj1.x - 2.f * acc[1][ct][0]);
        part += s1.y * (sic + sj1.y - 2.f * acc[1][ct][1]);
        part += s1.z * (sic + sj1.z - 2.f * acc[1][ct][2]);
        part += s1.w * (sic + sj1.w - 2.f * acc[1][ct][3]);
    }

    #pragma unroll
    for (int off = 32; off > 0; off >>= 1) part += __shfl_down(part, off);
    if (l == 0) red[w] = part;
    __syncthreads();
    if (tid == 0)
        partials[blockIdx.y * gridDim.x + blockIdx.x] = (red[0] + red[1]) + (red[2] + red[3]);
}

__global__ void reduce_kernel(const float* __restrict__ partials, float* __restrict__ out) {
    __shared__ float sm[256];
    const int t = threadIdx.x;
    float s = 0.f;
    for (int i = t; i < NTILE * NTILE; i += 256) s += partials[i];
    sm[t] = s;
    __syncthreads();
    for (int off = 128; off > 0; off >>= 1) {
        if (t < off) sm[t] += sm[t + off];
        __syncthreads();
    }
    if (t == 0) out[0] = sm[0];
}

extern "C" void kernel_launch(void* const* d_in, const int* in_sizes, int n_in,
                              void* d_out, int out_size, void* d_ws, size_t ws_size,
                              hipStream_t stream) {
    const float* F = (const float*)d_in[0];
    const float* S = (const float*)d_in[1];
    float* sq       = (float*)d_ws;                       // 32 KB
    float* partials = sq + NN;                            // 16 KB
    ushort* Fbf     = (ushort*)((char*)d_ws + 48 * 1024); // 2 MB
    float* out      = (float*)d_out;

    const size_t need = 48 * 1024 + (size_t)NN * DD * 2 + 256;
    const int fast = (ws_size >= need) ? 1 : 0;

    prep_kernel<<<NN / 4, 256, 0, stream>>>(F, Fbf, sq, fast);
    dim3 grid(NTILE, NTILE);
    if (fast)
        tile_kernel<<<grid, 512, 0, stream>>>(Fbf, S, sq, partials);
    else
        tile_fb_kernel<<<grid, 256, 0, stream>>>(F, S, sq, partials);
    reduce_kernel<<<1, 256, 0, stream>>>(partials, out);
}

// Round 12
// 64.716 us; speedup vs baseline: 1.0120x; 1.0120x over previous
//
#include <hip/hip_runtime.h>

#define NN 8192
#define DD 128
#define BM 128
#define NTILE (NN / BM)   // 64

typedef __attribute__((ext_vector_type(8))) short bf16x8;
typedef __attribute__((ext_vector_type(4))) float f32x4;

__device__ __forceinline__ ushort f2bf(float x) {
    unsigned u = __float_as_uint(x);
    unsigned r = u + 0x7FFFu + ((u >> 16) & 1u);
    return (ushort)(r >> 16);
}

__device__ __forceinline__ void async16(void* lds, const void* g) {
    __builtin_amdgcn_global_load_lds(
        (const __attribute__((address_space(1))) unsigned*)g,
        (__attribute__((address_space(3))) unsigned*)lds, 16, 0, 0);
}
__device__ __forceinline__ void async4(void* lds, const void* g) {
    __builtin_amdgcn_global_load_lds(
        (const __attribute__((address_space(1))) unsigned*)g,
        (__attribute__((address_space(3))) unsigned*)lds, 4, 0, 0);
}

// Kernel 0: sq[i] = ||f_i||^2 (always); Fbf = bf16(F) (if doFbf).
__global__ void prep_kernel(const float* __restrict__ F, ushort* __restrict__ Fbf,
                            float* __restrict__ sq, int doFbf) {
    int gtid = blockIdx.x * blockDim.x + threadIdx.x;
    int row  = gtid >> 6;
    int lane = threadIdx.x & 63;
    const float2 v = *(const float2*)(F + (size_t)row * DD + lane * 2);
    if (doFbf)
        ((ushort2*)(Fbf + (size_t)row * DD))[lane] = make_ushort2(f2bf(v.x), f2bf(v.y));
    float s = v.x * v.x + v.y * v.y;
    #pragma unroll
    for (int off = 32; off > 0; off >>= 1) s += __shfl_down(s, off);
    if (lane == 0) sq[row] = s;
}

// Kernel 1 (fast): per 128x128 S-tile, partial = sum S_ij*(sq_i+sq_j-2*f_i.f_j).
// R10 structure but 1024-thread blocks: 16 waves, each owns 16 j-cols x 64
// i-rows -> per-thread state sv[4]+acc[4]+afrag[4] ~= 56-62 VGPR. With
// launch_bounds(1024,8) the VGPR cap is 64 -> 8 waves/SIMD -> 2 blocks/CU =
// 32 waves/CU (2x R10's 16): more phase stagger to keep the S stream on.
__global__ __launch_bounds__(1024, 8) void tile_kernel(
        const ushort* __restrict__ Fbf, const float* __restrict__ S,
        const float* __restrict__ sq, float* __restrict__ partials) {
    __shared__ ushort lI[BM * DD];   // F_i panel (B-operand), swizzled (32 KB)
    __shared__ ushort lJ[BM * DD];   // F_j panel (A-operand), swizzled (32 KB)
    __shared__ float  sqi[BM];
    __shared__ float  sqj[BM];
    __shared__ float  red[16];

    const int gi = blockIdx.y * BM, gj = blockIdx.x * BM;
    const int tid = threadIdx.x;
    const int w = tid >> 6, l = tid & 63;   // w: 0..15
    const int fr = l & 15;
    const int g  = l >> 4;
    const int jw  = (w & 7) * 16;           // wave's 16-col j window
    const int ct0 = (w >> 3) * 4;           // wave's 4-slice i window (64 rows)

    // ---- (1) stage panels: 32 chunks each; wave handles 2 chunks/panel ----
    #pragma unroll
    for (int it = 0; it < 2; ++it) {
        const int chunk = it * 16 + w;           // 1 KB chunk = 4 rows
        const int row = chunk * 4 + (l >> 4);
        const int src = ((l & 15) * 16) ^ ((row & 7) << 4);
        async16((char*)lI + chunk * 1024, (const char*)(Fbf + (size_t)(gi + row) * DD) + src);
        async16((char*)lJ + chunk * 1024, (const char*)(Fbf + (size_t)(gj + row) * DD) + src);
    }
    if (w < 4) {
        float* dstb = (w < 2 ? sqi : sqj) + (w & 1) * 64;
        const float* srcb = sq + (w < 2 ? gi : gj) + (w & 1) * 64 + l;
        async4(dstb, srcb);
    }
    __syncthreads();

    // ---- (2) S loads after barrier: fly under ds_reads + MFMAs ----
    f32x4 sv[4];
    #pragma unroll
    for (int c = 0; c < 4; ++c)
        sv[c] = *(const f32x4*)(S + (size_t)(gi + (ct0 + c) * 16 + fr) * NN +
                                gj + jw + g * 4);
    __builtin_amdgcn_sched_barrier(0);   // pin: S issued before MFMA/ds_read

    // ---- (3) A fragments from F_j panel ----
    bf16x8 afrag[4];
    {
        const int row = jw + fr;
        const int sw  = (row & 7) << 4;
        #pragma unroll
        for (int kk = 0; kk < 4; ++kk)
            afrag[kk] = *(const bf16x8*)((const char*)lJ + row * 256 +
                                         ((kk * 64 + g * 16) ^ sw));
    }

    f32x4 acc[4];
    #pragma unroll
    for (int c = 0; c < 4; ++c) acc[c] = (f32x4){0.f, 0.f, 0.f, 0.f};

    // ---- (4) MFMA: D = F_j . F_i^T over this wave's 4 i-slices ----
    #pragma unroll
    for (int c = 0; c < 4; ++c) {
        const int row = (ct0 + c) * 16 + fr;
        const int sw  = (row & 7) << 4;
        #pragma unroll
        for (int kk = 0; kk < 4; ++kk) {
            const bf16x8 bfrag = *(const bf16x8*)((const char*)lI + row * 256 +
                                                  ((kk * 64 + g * 16) ^ sw));
            acc[c] = __builtin_amdgcn_mfma_f32_16x16x32_bf16(afrag[kk], bfrag, acc[c], 0, 0, 0);
        }
    }

    // ---- (5) consume: part += S * (sq_i + sq_j - 2*P); sq from LDS ----
    const float4 sjv = *(const float4*)(sqj + jw + g * 4);
    float part0 = 0.f, part1 = 0.f;
    #pragma unroll
    for (int c = 0; c < 4; ++c) {
        const float sic = sqi[(ct0 + c) * 16 + fr];
        const f32x4 s4 = sv[c];
        part0 += s4.x * ((sic + sjv.x) - 2.f * acc[c][0]);
        part1 += s4.y * ((sic + sjv.y) - 2.f * acc[c][1]);
        part0 += s4.z * ((sic + sjv.z) - 2.f * acc[c][2]);
        part1 += s4.w * ((sic + sjv.w) - 2.f * acc[c][3]);
    }
    float part = part0 + part1;

    // ---- (6) deterministic block reduction ----
    #pragma unroll
    for (int off = 32; off > 0; off >>= 1) part += __shfl_down(part, off);
    if (l == 0) red[w] = part;
    __syncthreads();
    if (tid == 0) {
        float r = 0.f;
        #pragma unroll
        for (int k = 0; k < 16; ++k) r += red[k];
        partials[blockIdx.y * gridDim.x + blockIdx.x] = r;
    }
}

// ---------------- fallback path (tiny workspace): R2-style ----------------
__global__ __launch_bounds__(256, 2) void tile_fb_kernel(
        const float* __restrict__ F, const float* __restrict__ S,
        const float* __restrict__ sq, float* __restrict__ partials) {
    __shared__ ushort lI[BM * DD];
    __shared__ ushort lJ[BM * DD];
    __shared__ float  sqi[BM];
    __shared__ float  sqj[BM];
    __shared__ float  red[4];

    const int gi = blockIdx.y * BM, gj = blockIdx.x * BM;
    const int tid = threadIdx.x;
    const int w = tid >> 6, l = tid & 63;

    const int r0 = tid >> 5;
    const int c4 = (tid & 31) * 4;
    #pragma unroll
    for (int it = 0; it < 16; ++it) {
        const int row = it * 8 + r0;
        const float4 va = *(const float4*)(F + (size_t)(gi + row) * DD + c4);
        const float4 vb = *(const float4*)(F + (size_t)(gj + row) * DD + c4);
        int byte = row * 256 + c4 * 2;
        byte ^= (row & 7) << 4;
        *(ushort4*)((char*)lI + byte) =
            make_ushort4(f2bf(va.x), f2bf(va.y), f2bf(va.z), f2bf(va.w));
        *(ushort4*)((char*)lJ + byte) =
            make_ushort4(f2bf(vb.x), f2bf(vb.y), f2bf(vb.z), f2bf(vb.w));
    }
    if (tid < 128) sqi[tid] = sq[gi + tid];
    else           sqj[tid - 128] = sq[gj + tid - 128];
    __syncthreads();

    const int fr = l & 15;
    const int g  = l >> 4;
    const int jw = w * 32;

    float4 sv0[8], sv1[8];
    #pragma unroll
    for (int ct = 0; ct < 8; ++ct) {
        const float* srow = S + (size_t)(gi + ct * 16 + fr) * NN + gj + jw + g * 4;
        sv0[ct] = *(const float4*)(srow);
        sv1[ct] = *(const float4*)(srow + 16);
    }

    bf16x8 afrag[2][4];
    #pragma unroll
    for (int kk = 0; kk < 4; ++kk) {
        int row = jw + fr;
        int byte = row * 256 + kk * 64 + g * 16; byte ^= (row & 7) << 4;
        afrag[0][kk] = *(const bf16x8*)((const char*)lJ + byte);
        row = jw + 16 + fr;
        byte = row * 256 + kk * 64 + g * 16; byte ^= (row & 7) << 4;
        afrag[1][kk] = *(const bf16x8*)((const char*)lJ + byte);
    }

    f32x4 acc[2][8];
    #pragma unroll
    for (int ct = 0; ct < 8; ++ct) {
        acc[0][ct] = (f32x4){0.f, 0.f, 0.f, 0.f};
        acc[1][ct] = (f32x4){0.f, 0.f, 0.f, 0.f};
    }
    #pragma unroll
    for (int ct = 0; ct < 8; ++ct) {
        #pragma unroll
        for (int kk = 0; kk < 4; ++kk) {
            const int row = ct * 16 + fr;
            int byte = row * 256 + kk * 64 + g * 16; byte ^= (row & 7) << 4;
            const bf16x8 bfrag = *(const bf16x8*)((const char*)lI + byte);
            acc[0][ct] = __builtin_amdgcn_mfma_f32_16x16x32_bf16(afrag[0][kk], bfrag, acc[0][ct], 0, 0, 0);
            acc[1][ct] = __builtin_amdgcn_mfma_f32_16x16x32_bf16(afrag[1][kk], bfrag, acc[1][ct], 0, 0, 0);
        }
    }

    const float4 sj0 = *(const float4*)(sqj + jw + g * 4);
    const float4 sj1 = *(const float4*)(sqj + jw + 16 + g * 4);
    float part = 0.f;
    #pragma unroll
    for (int ct = 0; ct < 8; ++ct) {
        const float sic = sqi[ct * 16 + fr];
        const float4 s0 = sv0[ct], s1 = sv1[ct];
        part += s0.x * (sic + sj0.x - 2.f * acc[0][ct][0]);
        part += s0.y * (sic + sj0.y - 2.f * acc[0][ct][1]);
        part += s0.z * (sic + sj0.z - 2.f * acc[0][ct][2]);
        part += s0.w * (sic + sj0.w - 2.f * acc[0][ct][3]);
        part += s1.x * (sic + sj1.x - 2.f * acc[1][ct][0]);
        part += s1.y * (sic + sj1.y - 2.f * acc[1][ct][1]);
        part += s1.z * (sic + sj1.z - 2.f * acc[1][ct][2]);
        part += s1.w * (sic + sj1.w - 2.f * acc[1][ct][3]);
    }

    #pragma unroll
    for (int off = 32; off > 0; off >>= 1) part += __shfl_down(part, off);
    if (l == 0) red[w] = part;
    __syncthreads();
    if (tid == 0)
        partials[blockIdx.y * gridDim.x + blockIdx.x] = (red[0] + red[1]) + (red[2] + red[3]);
}

__global__ void reduce_kernel(const float* __restrict__ partials, float* __restrict__ out) {
    __shared__ float sm[256];
    const int t = threadIdx.x;
    float s = 0.f;
    for (int i = t; i < NTILE * NTILE; i += 256) s += partials[i];
    sm[t] = s;
    __syncthreads();
    for (int off = 128; off > 0; off >>= 1) {
        if (t < off) sm[t] += sm[t + off];
        __syncthreads();
    }
    if (t == 0) out[0] = sm[0];
}

extern "C" void kernel_launch(void* const* d_in, const int* in_sizes, int n_in,
                              void* d_out, int out_size, void* d_ws, size_t ws_size,
                              hipStream_t stream) {
    const float* F = (const float*)d_in[0];
    const float* S = (const float*)d_in[1];
    float* sq       = (float*)d_ws;                       // 32 KB
    float* partials = sq + NN;                            // 16 KB
    ushort* Fbf     = (ushort*)((char*)d_ws + 48 * 1024); // 2 MB
    float* out      = (float*)d_out;

    const size_t need = 48 * 1024 + (size_t)NN * DD * 2 + 256;
    const int fast = (ws_size >= need) ? 1 : 0;

    prep_kernel<<<NN / 4, 256, 0, stream>>>(F, Fbf, sq, fast);
    dim3 grid(NTILE, NTILE);
    if (fast)
        tile_kernel<<<grid, 1024, 0, stream>>>(Fbf, S, sq, partials);
    else
        tile_fb_kernel<<<grid, 256, 0, stream>>>(F, S, sq, partials);
    reduce_kernel<<<1, 256, 0, stream>>>(partials, out);
}